// Round 4
// baseline (507.732 us; speedup 1.0000x reference)
//
#include <hip/hip_runtime.h>
#include <hip/hip_bf16.h>

// TransformerBlock: pre-LN attn + FFN, bf16 MFMA compute, fp32 I/O.
// M=4096 tokens (b=2 x n=2048), EMB=1024, 16 heads x 64, FFN=4096.

using bf16 = __hip_bfloat16;
using bf16x8 = __attribute__((ext_vector_type(8))) short;   // 8 bf16 = 4 VGPRs
using f32x4 = __attribute__((ext_vector_type(4))) float;

#define MFMA16(a, b, c) __builtin_amdgcn_mfma_f32_16x16x32_bf16((a), (b), (c), 0, 0, 0)

enum { EPI_BF16 = 0, EPI_BIAS_RES_F32 = 1, EPI_GELU_BF16 = 2 };

__device__ __forceinline__ float cvt_f(float x) { return x; }
__device__ __forceinline__ float cvt_f(bf16 x) { return __bfloat162float(x); }

__device__ __forceinline__ float gelu_f(float x) {
  float z = 0.7978845608028654f * (x + 0.044715f * x * x * x);
  z = fminf(fmaxf(z, -15.f), 15.f);
  float e = __expf(2.f * z);
  return 0.5f * x * (1.f + (e - 1.f) / (e + 1.f));
}

// global->LDS staging, 16B per lane. lds_base must be wave-uniform; HW writes
// base + lane*16 (guide m97/m104). Fallback path does the same via registers.
__device__ __forceinline__ void stage16(const bf16* g, bf16* lds_base, int lane) {
#if defined(__has_builtin) && __has_builtin(__builtin_amdgcn_global_load_lds)
  __builtin_amdgcn_global_load_lds(
      (__attribute__((address_space(1))) void*)(void*)g,
      (__attribute__((address_space(3))) void*)lds_base, 16, 0, 0);
#else
  *(int4*)(lds_base + lane * 8) = *(const int4*)g;
#endif
}

// ---------------- transpose + convert to bf16 ----------------
// src [R][C] (ld=sld) -> dst [C][R] (ld=dld). grid = (C/32, R/32), 256 thr.
template <typename T>
__global__ __launch_bounds__(256) void transpose_bf16_k(
    const T* __restrict__ src, bf16* __restrict__ dst, int sld, int dld) {
  __shared__ float tile[32][33];
  const int tx = threadIdx.x & 31, ty = threadIdx.x >> 5;  // ty: 0..7
  const size_t r0 = (size_t)blockIdx.y * 32, c0 = (size_t)blockIdx.x * 32;
#pragma unroll
  for (int i = 0; i < 32; i += 8)
    tile[ty + i][tx] = cvt_f(src[(r0 + ty + i) * sld + c0 + tx]);
  __syncthreads();
#pragma unroll
  for (int i = 0; i < 32; i += 8)
    dst[(c0 + ty + i) * dld + r0 + tx] = __float2bfloat16(tile[tx][ty + i]);
}

// ---------------- LayerNorm (row=1024) -> bf16 ----------------
__global__ __launch_bounds__(256) void ln_fwd_k(
    const float* __restrict__ x, const float* __restrict__ gam,
    const float* __restrict__ bet, bf16* __restrict__ out) {
  const int row = blockIdx.x;
  const float4 v = ((const float4*)(x + (size_t)row * 1024))[threadIdx.x];
  float s = v.x + v.y + v.z + v.w;
  float sq = v.x * v.x + v.y * v.y + v.z * v.z + v.w * v.w;
#pragma unroll
  for (int off = 32; off; off >>= 1) {
    s += __shfl_down(s, off);
    sq += __shfl_down(sq, off);
  }
  __shared__ float rs[4], rq[4];
  const int w = threadIdx.x >> 6, lane = threadIdx.x & 63;
  if (lane == 0) { rs[w] = s; rq[w] = sq; }
  __syncthreads();
  s = rs[0] + rs[1] + rs[2] + rs[3];
  sq = rq[0] + rq[1] + rq[2] + rq[3];
  const float mean = s * (1.f / 1024.f);
  const float var = sq * (1.f / 1024.f) - mean * mean;
  const float rstd = rsqrtf(var + 1e-5f);
  const float4 g4 = ((const float4*)gam)[threadIdx.x];
  const float4 b4 = ((const float4*)bet)[threadIdx.x];
  short4 pk;
  bf16* hp = (bf16*)&pk;
  hp[0] = __float2bfloat16((v.x - mean) * rstd * g4.x + b4.x);
  hp[1] = __float2bfloat16((v.y - mean) * rstd * g4.y + b4.y);
  hp[2] = __float2bfloat16((v.z - mean) * rstd * g4.z + b4.z);
  hp[3] = __float2bfloat16((v.w - mean) * rstd * g4.w + b4.w);
  ((short4*)(out + (size_t)row * 1024))[threadIdx.x] = pk;
}

// ---------------- GEMM: C[M][N] = A[M][K] * BT[N][K]^T ----------------
// 128x128 tile, BK=64, 4 waves (2x2) each 64x64 via 4x4 mfma_16x16x32 frags.
template <int EPI>
__global__ __launch_bounds__(256) void gemm_bt_k(
    const bf16* __restrict__ A, const bf16* __restrict__ BT,
    void* __restrict__ Cout, const float* __restrict__ bias,
    const float* __restrict__ res, int M, int N, int K) {
  __shared__ bf16 As[128 * 64];
  __shared__ bf16 Bs[128 * 64];
  const int tid = threadIdx.x;
  const int w = tid >> 6, lane = tid & 63;
  const int wr = w >> 1, wc = w & 1;
  const int lr = lane & 15, lk = lane >> 4;
  const size_t rowTile = (size_t)blockIdx.y * 128;
  const size_t colTile = (size_t)blockIdx.x * 128;

  const bf16* Ag = A + rowTile * K;
  const bf16* Bg = BT + colTile * K;
  const int srow = lane >> 3;         // 0..7
  const int scol = (lane & 7) * 8;    // element col, 16B chunks

  const f32x4 z4 = {0.f, 0.f, 0.f, 0.f};
  f32x4 acc[4][4];
#pragma unroll
  for (int i = 0; i < 4; ++i)
#pragma unroll
    for (int j = 0; j < 4; ++j) acc[i][j] = z4;

  for (int kb = 0; kb < K; kb += 64) {
#pragma unroll
    for (int i = 0; i < 4; ++i) {
      const int r = w * 32 + i * 8;  // wave-uniform base row of this 8-row issue
      stage16(Ag + (size_t)(r + srow) * K + kb + scol, &As[r * 64], lane);
      stage16(Bg + (size_t)(r + srow) * K + kb + scol, &Bs[r * 64], lane);
    }
    __syncthreads();
#pragma unroll
    for (int kk = 0; kk < 2; ++kk) {
      bf16x8 af[4], bg[4];
#pragma unroll
      for (int mi = 0; mi < 4; ++mi)
        af[mi] = *(const bf16x8*)&As[(wr * 64 + mi * 16 + lr) * 64 + kk * 32 + lk * 8];
#pragma unroll
      for (int ni = 0; ni < 4; ++ni)
        bg[ni] = *(const bf16x8*)&Bs[(wc * 64 + ni * 16 + lr) * 64 + kk * 32 + lk * 8];
#pragma unroll
      for (int mi = 0; mi < 4; ++mi)
#pragma unroll
        for (int ni = 0; ni < 4; ++ni)
          acc[mi][ni] = MFMA16(af[mi], bg[ni], acc[mi][ni]);
    }
    __syncthreads();
  }

  // epilogue. C/D layout (m89): col = lane&15, row = (lane>>4)*4 + reg.
  const size_t baseRow = rowTile + wr * 64;
  const size_t baseCol = colTile + wc * 64;
#pragma unroll
  for (int mi = 0; mi < 4; ++mi)
#pragma unroll
    for (int ni = 0; ni < 4; ++ni) {
      const size_t col = baseCol + ni * 16 + lr;
#pragma unroll
      for (int r = 0; r < 4; ++r) {
        const size_t row = baseRow + mi * 16 + lk * 4 + r;
        const size_t idx = row * (size_t)N + col;
        const float v = acc[mi][ni][r];
        if constexpr (EPI == EPI_BF16) {
          ((bf16*)Cout)[idx] = __float2bfloat16(v);
        } else if constexpr (EPI == EPI_BIAS_RES_F32) {
          ((float*)Cout)[idx] = v + bias[col] + res[idx];
        } else {  // EPI_GELU_BF16
          ((bf16*)Cout)[idx] = __float2bfloat16(gelu_f(v + bias[col]));
        }
      }
    }
}

// ---------------- Flash attention (causal) ----------------
// grid (32 qblocks, 16 heads, 2 batches), 256 thr = 4 waves x 16 q-rows.
// QKV: [4096][3072] bf16 (Q|K|V). VT: [1024][4096] bf16. ctx: [4096][1024].
__global__ __launch_bounds__(256) void attn_fwd_k(
    const bf16* __restrict__ QKV, const bf16* __restrict__ VT,
    bf16* __restrict__ ctx) {
  const int qb = blockIdx.x, head = blockIdx.y, batch = blockIdx.z;
  const int tid = threadIdx.x;
  const int w = tid >> 6, lane = tid & 63;
  const int lr = lane & 15, lk = lane >> 4;
  const int qrow_w = qb * 64 + w * 16;  // within batch

  __shared__ bf16 Ks[64 * 64];
  __shared__ bf16 Vs[64 * 64];          // V^T tile: [d][key]
  __shared__ bf16 Ps[4][16 * 64];

  bf16x8 aq0, aq1;
  {
    const bf16* qp = QKV + (size_t)(batch * 2048 + qrow_w + lr) * 3072 + head * 64 + lk * 8;
    aq0 = *(const bf16x8*)qp;
    aq1 = *(const bf16x8*)(qp + 32);
  }
  const f32x4 z4 = {0.f, 0.f, 0.f, 0.f};
  float m0[4], l0[4];
  f32x4 co[4];
#pragma unroll
  for (int r = 0; r < 4; ++r) { m0[r] = -1e30f; l0[r] = 0.f; }
#pragma unroll
  for (int nd = 0; nd < 4; ++nd) co[nd] = z4;

  const bf16* kbase_p = QKV + (size_t)(batch * 2048) * 3072 + 1024 + head * 64;
  const bf16* vbase_p = VT + (size_t)(head * 64) * 4096 + batch * 2048;
  const int srow = tid >> 3;         // 0..31
  const int scol = (tid & 7) * 8;

  for (int kb = 0; kb <= qb; ++kb) {
    const int kb64 = kb * 64;
    // stage K [key][d] and V^T [d][key] tiles (coalesced 16B per lane)
    *(int4*)&Ks[srow * 64 + scol]        = *(const int4*)&kbase_p[(size_t)(kb64 + srow) * 3072 + scol];
    *(int4*)&Ks[(srow + 32) * 64 + scol] = *(const int4*)&kbase_p[(size_t)(kb64 + srow + 32) * 3072 + scol];
    *(int4*)&Vs[srow * 64 + scol]        = *(const int4*)&vbase_p[(size_t)srow * 4096 + kb64 + scol];
    *(int4*)&Vs[(srow + 32) * 64 + scol] = *(const int4*)&vbase_p[(size_t)(srow + 32) * 4096 + kb64 + scol];
    __syncthreads();

    // S = Q K^T  (16 q-rows x 64 keys per wave)
    f32x4 sv[4];
#pragma unroll
    for (int ni = 0; ni < 4; ++ni) {
      const bf16x8 bk0 = *(const bf16x8*)&Ks[(ni * 16 + lr) * 64 + lk * 8];
      const bf16x8 bk1 = *(const bf16x8*)&Ks[(ni * 16 + lr) * 64 + 32 + lk * 8];
      f32x4 z = z4;
      z = MFMA16(aq0, bk0, z);
      z = MFMA16(aq1, bk1, z);
      sv[ni] = z;
    }
    // scale + causal mask (key > qrow -> -inf)
    const bool diag = (kb == qb);
#pragma unroll
    for (int ni = 0; ni < 4; ++ni)
#pragma unroll
      for (int r = 0; r < 4; ++r) {
        float v = sv[ni][r] * 0.125f;
        if (diag && (kb64 + ni * 16 + lr > qrow_w + lk * 4 + r)) v = -1e30f;
        sv[ni][r] = v;
      }
    // online softmax: row max over 16 lanes (col dim) + 4 col-groups
    float fac[4];
#pragma unroll
    for (int r = 0; r < 4; ++r) {
      float mx = fmaxf(fmaxf(sv[0][r], sv[1][r]), fmaxf(sv[2][r], sv[3][r]));
      mx = fmaxf(mx, __shfl_xor(mx, 1));
      mx = fmaxf(mx, __shfl_xor(mx, 2));
      mx = fmaxf(mx, __shfl_xor(mx, 4));
      mx = fmaxf(mx, __shfl_xor(mx, 8));
      const float mn = fmaxf(m0[r], mx);
      fac[r] = __expf(m0[r] - mn);
      m0[r] = mn;
    }
#pragma unroll
    for (int ni = 0; ni < 4; ++ni)
#pragma unroll
      for (int r = 0; r < 4; ++r) sv[ni][r] = __expf(sv[ni][r] - m0[r]);
#pragma unroll
    for (int r = 0; r < 4; ++r) {
      float ps = sv[0][r] + sv[1][r] + sv[2][r] + sv[3][r];
      ps += __shfl_xor(ps, 1);
      ps += __shfl_xor(ps, 2);
      ps += __shfl_xor(ps, 4);
      ps += __shfl_xor(ps, 8);
      l0[r] = l0[r] * fac[r] + ps;
    }
    // P -> LDS (per-wave slice, C-layout -> [qrow][key])
#pragma unroll
    for (int ni = 0; ni < 4; ++ni)
#pragma unroll
      for (int r = 0; r < 4; ++r)
        Ps[w][(lk * 4 + r) * 64 + ni * 16 + lr] = __float2bfloat16(sv[ni][r]);
    // rescale running ctx
#pragma unroll
    for (int nd = 0; nd < 4; ++nd)
#pragma unroll
      for (int r = 0; r < 4; ++r) co[nd][r] *= fac[r];
    // ctx += P V
#pragma unroll
    for (int kk = 0; kk < 2; ++kk) {
      const bf16x8 ap = *(const bf16x8*)&Ps[w][lr * 64 + kk * 32 + lk * 8];
#pragma unroll
      for (int nd = 0; nd < 4; ++nd) {
        const bf16x8 bv = *(const bf16x8*)&Vs[(nd * 16 + lr) * 64 + kk * 32 + lk * 8];
        co[nd] = MFMA16(ap, bv, co[nd]);
      }
    }
    __syncthreads();
  }
  // write ctx[token][head*64+d] (bf16)
#pragma unroll
  for (int nd = 0; nd < 4; ++nd)
#pragma unroll
    for (int r = 0; r < 4; ++r) {
      const float v = co[nd][r] / l0[r];
      const size_t row = (size_t)(batch * 2048 + qrow_w + lk * 4 + r);
      ctx[row * 1024 + head * 64 + nd * 16 + lr] = __float2bfloat16(v);
    }
}

// ---------------- launch ----------------
extern "C" void kernel_launch(void* const* d_in, const int* in_sizes, int n_in,
                              void* d_out, int out_size, void* d_ws, size_t ws_size,
                              hipStream_t stream) {
  const float* x    = (const float*)d_in[0];
  const float* Wq   = (const float*)d_in[1];
  const float* Wk   = (const float*)d_in[2];
  const float* Wv   = (const float*)d_in[3];
  const float* Wo   = (const float*)d_in[4];
  const float* bo   = (const float*)d_in[5];
  const float* W1   = (const float*)d_in[6];
  const float* b1   = (const float*)d_in[7];
  const float* W2   = (const float*)d_in[8];
  const float* b2   = (const float*)d_in[9];
  const float* ln1s = (const float*)d_in[10];
  const float* ln1b = (const float*)d_in[11];
  const float* ln2s = (const float*)d_in[12];
  const float* ln2b = (const float*)d_in[13];
  float* out = (float*)d_out;

  char* ws = (char*)d_ws;
  const size_t MB = 1ull << 20;
  bf16* WqkvT = (bf16*)(ws + 0);        // [3072][1024]  (Wq|Wk|Wv transposed)
  bf16* WoT   = (bf16*)(ws + 6 * MB);   // [1024][1024]
  bf16* W1T   = (bf16*)(ws + 8 * MB);   // [4096][1024]
  bf16* W2T   = (bf16*)(ws + 16 * MB);  // [1024][4096]
  bf16* h1    = (bf16*)(ws + 24 * MB);  // [4096][1024]  (reused as h2)
  bf16* QKV   = (bf16*)(ws + 32 * MB);  // [4096][3072]
  bf16* VT    = (bf16*)(ws + 56 * MB);  // [1024][4096]
  bf16* f1    = (bf16*)(ws + 32 * MB);  // [4096][4096]  overlays QKV+VT (dead by then)
  bf16* ctx   = (bf16*)(ws + 64 * MB);  // [4096][1024]
  // x1 (fp32) lives in d_out. Total ws: 72 MB.

  const dim3 T(256);

  // weight transposes + fp32->bf16
  transpose_bf16_k<float><<<dim3(32, 32), T, 0, stream>>>(Wq, WqkvT, 1024, 1024);
  transpose_bf16_k<float><<<dim3(32, 32), T, 0, stream>>>(Wk, WqkvT + 1024 * 1024, 1024, 1024);
  transpose_bf16_k<float><<<dim3(32, 32), T, 0, stream>>>(Wv, WqkvT + 2048 * 1024, 1024, 1024);
  transpose_bf16_k<float><<<dim3(32, 32), T, 0, stream>>>(Wo, WoT, 1024, 1024);
  transpose_bf16_k<float><<<dim3(128, 32), T, 0, stream>>>(W1, W1T, 4096, 1024);
  transpose_bf16_k<float><<<dim3(32, 128), T, 0, stream>>>(W2, W2T, 1024, 4096);

  // LN1 -> h1 (bf16)
  ln_fwd_k<<<4096, T, 0, stream>>>(x, ln1s, ln1b, h1);

  // QKV = h1 @ [Wq|Wk|Wv]   -> [4096][3072] bf16
  gemm_bt_k<EPI_BF16><<<dim3(24, 32), T, 0, stream>>>(
      h1, WqkvT, QKV, nullptr, nullptr, 4096, 3072, 1024);

  // V^T  [1024][4096] for PV fragment reads
  transpose_bf16_k<bf16><<<dim3(32, 128), T, 0, stream>>>(QKV + 2048, VT, 3072, 4096);

  // attention -> ctx bf16
  attn_fwd_k<<<dim3(32, 16, 2), T, 0, stream>>>(QKV, VT, ctx);

  // x1 = ctx @ Wo + bo + x   -> d_out (fp32)
  gemm_bt_k<EPI_BIAS_RES_F32><<<dim3(8, 32), T, 0, stream>>>(
      ctx, WoT, out, bo, x, 4096, 1024, 1024);

  // LN2(x1) -> h2 (reuse h1)
  ln_fwd_k<<<4096, T, 0, stream>>>(out, ln2s, ln2b, h1);

  // f1 = gelu(h2 @ W1 + b1)  -> [4096][4096] bf16
  gemm_bt_k<EPI_GELU_BF16><<<dim3(32, 32), T, 0, stream>>>(
      h1, W1T, f1, b1, nullptr, 4096, 4096, 1024);

  // out = f1 @ W2 + b2 + x1  (read-modify-write on d_out)
  gemm_bt_k<EPI_BIAS_RES_F32><<<dim3(8, 32), T, 0, stream>>>(
      f1, W2T, out, b2, out, 4096, 1024, 4096);
}

// Round 5
// 424.310 us; speedup vs baseline: 1.1966x; 1.1966x over previous
//
#include <hip/hip_runtime.h>
#include <hip/hip_bf16.h>

// TransformerBlock: pre-LN attn + FFN, bf16 MFMA compute, fp32 I/O.
// M=4096 tokens (b=2 x n=2048), EMB=1024, 16 heads x 64, FFN=4096.

using bf16 = __hip_bfloat16;
using bf16x8 = __attribute__((ext_vector_type(8))) short;   // 8 bf16 = 4 VGPRs
using f32x4 = __attribute__((ext_vector_type(4))) float;

#define MFMA16(a, b, c) __builtin_amdgcn_mfma_f32_16x16x32_bf16((a), (b), (c), 0, 0, 0)

enum { EPI_BF16 = 0, EPI_BIAS_RES_F32 = 1, EPI_GELU_BF16 = 2 };

__device__ __forceinline__ float cvt_f(float x) { return x; }
__device__ __forceinline__ float cvt_f(bf16 x) { return __bfloat162float(x); }

__device__ __forceinline__ float gelu_f(float x) {
  float z = 0.7978845608028654f * (x + 0.044715f * x * x * x);
  z = fminf(fmaxf(z, -15.f), 15.f);
  float e = __expf(2.f * z);
  return 0.5f * x * (1.f + (e - 1.f) / (e + 1.f));
}

// global->LDS staging, 16B per lane. lds_base must be wave-uniform; HW writes
// base + lane*16 (guide m97/m104).
__device__ __forceinline__ void stage16(const bf16* g, bf16* lds_base, int lane) {
#if defined(__has_builtin) && __has_builtin(__builtin_amdgcn_global_load_lds)
  __builtin_amdgcn_global_load_lds(
      (__attribute__((address_space(1))) void*)(void*)g,
      (__attribute__((address_space(3))) void*)lds_base, 16, 0, 0);
#else
  *(int4*)(lds_base + lane * 8) = *(const int4*)g;
#endif
}

// ---------------- transpose + convert to bf16 ----------------
template <typename T>
__global__ __launch_bounds__(256) void transpose_bf16_k(
    const T* __restrict__ src, bf16* __restrict__ dst, int sld, int dld) {
  __shared__ float tile[32][33];
  const int tx = threadIdx.x & 31, ty = threadIdx.x >> 5;
  const size_t r0 = (size_t)blockIdx.y * 32, c0 = (size_t)blockIdx.x * 32;
#pragma unroll
  for (int i = 0; i < 32; i += 8)
    tile[ty + i][tx] = cvt_f(src[(r0 + ty + i) * sld + c0 + tx]);
  __syncthreads();
#pragma unroll
  for (int i = 0; i < 32; i += 8)
    dst[(c0 + ty + i) * dld + r0 + tx] = __float2bfloat16(tile[tx][ty + i]);
}

// ---------------- LayerNorm (row=1024) -> bf16 ----------------
__global__ __launch_bounds__(256) void ln_fwd_k(
    const float* __restrict__ x, const float* __restrict__ gam,
    const float* __restrict__ bet, bf16* __restrict__ out) {
  const int row = blockIdx.x;
  const float4 v = ((const float4*)(x + (size_t)row * 1024))[threadIdx.x];
  float s = v.x + v.y + v.z + v.w;
  float sq = v.x * v.x + v.y * v.y + v.z * v.z + v.w * v.w;
#pragma unroll
  for (int off = 32; off; off >>= 1) {
    s += __shfl_down(s, off);
    sq += __shfl_down(sq, off);
  }
  __shared__ float rs[4], rq[4];
  const int w = threadIdx.x >> 6, lane = threadIdx.x & 63;
  if (lane == 0) { rs[w] = s; rq[w] = sq; }
  __syncthreads();
  s = rs[0] + rs[1] + rs[2] + rs[3];
  sq = rq[0] + rq[1] + rq[2] + rq[3];
  const float mean = s * (1.f / 1024.f);
  const float var = sq * (1.f / 1024.f) - mean * mean;
  const float rstd = rsqrtf(var + 1e-5f);
  const float4 g4 = ((const float4*)gam)[threadIdx.x];
  const float4 b4 = ((const float4*)bet)[threadIdx.x];
  short4 pk;
  bf16* hp = (bf16*)&pk;
  hp[0] = __float2bfloat16((v.x - mean) * rstd * g4.x + b4.x);
  hp[1] = __float2bfloat16((v.y - mean) * rstd * g4.y + b4.y);
  hp[2] = __float2bfloat16((v.z - mean) * rstd * g4.z + b4.z);
  hp[3] = __float2bfloat16((v.w - mean) * rstd * g4.w + b4.w);
  ((short4*)(out + (size_t)row * 1024))[threadIdx.x] = pk;
}

// ---------------- GEMM: C[M][N] = A[M][K] * BT[N][K]^T ----------------
// 128xBN tile, BK=64, 4 waves. BN=128: 2x2 waves, 64x64 each (acc 4x4).
// BN=64: 4x1 waves, 32x64 each (acc 2x4) -> 2x grid for small-N GEMMs.
template <int EPI, int BN>
__global__ __launch_bounds__(256) void gemm_bt_k(
    const bf16* __restrict__ A, const bf16* __restrict__ BT,
    void* __restrict__ Cout, const float* __restrict__ bias,
    const float* __restrict__ res, int M, int N, int K) {
  constexpr int WC = BN / 64;       // waves across cols
  constexpr int MI = 2 * WC;        // m-frags per wave (rows/wave = 32*WC)
  __shared__ bf16 As[128 * 64];
  __shared__ bf16 Bs[BN * 64];
  const int tid = threadIdx.x;
  const int w = tid >> 6, lane = tid & 63;
  const int wc = w % WC, wr = w / WC;
  const int lr = lane & 15, lk = lane >> 4;
  const size_t rowTile = (size_t)blockIdx.y * 128;
  const size_t colTile = (size_t)blockIdx.x * BN;

  const bf16* Ag = A + rowTile * K;
  const bf16* Bg = BT + colTile * K;
  const int srow = lane >> 3;         // 0..7
  const int scol = (lane & 7) * 8;    // element col, 16B chunks

  const f32x4 z4 = {0.f, 0.f, 0.f, 0.f};
  f32x4 acc[MI][4];
#pragma unroll
  for (int i = 0; i < MI; ++i)
#pragma unroll
    for (int j = 0; j < 4; ++j) acc[i][j] = z4;

  for (int kb = 0; kb < K; kb += 64) {
#pragma unroll
    for (int i = 0; i < 4; ++i) {
      const int r = w * 32 + i * 8;  // wave-uniform base row
      stage16(Ag + (size_t)(r + srow) * K + kb + scol, &As[r * 64], lane);
    }
#pragma unroll
    for (int i = 0; i < BN / 32; ++i) {
      const int r = w * (BN / 4) + i * 8;
      stage16(Bg + (size_t)(r + srow) * K + kb + scol, &Bs[r * 64], lane);
    }
    __syncthreads();
#pragma unroll
    for (int kk = 0; kk < 2; ++kk) {
      bf16x8 af[MI], bg[4];
#pragma unroll
      for (int mi = 0; mi < MI; ++mi)
        af[mi] = *(const bf16x8*)&As[(wr * (32 * WC) + mi * 16 + lr) * 64 + kk * 32 + lk * 8];
#pragma unroll
      for (int ni = 0; ni < 4; ++ni)
        bg[ni] = *(const bf16x8*)&Bs[(wc * 64 + ni * 16 + lr) * 64 + kk * 32 + lk * 8];
#pragma unroll
      for (int mi = 0; mi < MI; ++mi)
#pragma unroll
        for (int ni = 0; ni < 4; ++ni)
          acc[mi][ni] = MFMA16(af[mi], bg[ni], acc[mi][ni]);
    }
    __syncthreads();
  }

  // epilogue. C/D layout (m89): col = lane&15, row = (lane>>4)*4 + reg.
  const size_t baseRow = rowTile + wr * (32 * WC);
  const size_t baseCol = colTile + wc * 64;
#pragma unroll
  for (int mi = 0; mi < MI; ++mi)
#pragma unroll
    for (int ni = 0; ni < 4; ++ni) {
      const size_t col = baseCol + ni * 16 + lr;
#pragma unroll
      for (int r = 0; r < 4; ++r) {
        const size_t row = baseRow + mi * 16 + lk * 4 + r;
        const size_t idx = row * (size_t)N + col;
        const float v = acc[mi][ni][r];
        if constexpr (EPI == EPI_BF16) {
          ((bf16*)Cout)[idx] = __float2bfloat16(v);
        } else if constexpr (EPI == EPI_BIAS_RES_F32) {
          ((float*)Cout)[idx] = v + bias[col] + res[idx];
        } else {  // EPI_GELU_BF16
          ((bf16*)Cout)[idx] = __float2bfloat16(gelu_f(v + bias[col]));
        }
      }
    }
}

// ---------------- Flash attention (causal, paired q-tiles) ----------------
// grid (16 qpairs, 16 heads, 2 batches), 256 thr = 4 waves x 16 q-rows.
// Block handles q-tiles qbA=qp and qbB=31-qp -> uniform 33 steps/block and
// K/V staged once per pair. All LDS XOR-swizzled: 16B-chunk ^= (row&7).
__global__ __launch_bounds__(256) void attn_fwd_k(
    const bf16* __restrict__ QKV, const bf16* __restrict__ VT,
    bf16* __restrict__ ctx) {
  const int qp = blockIdx.x, head = blockIdx.y, batch = blockIdx.z;
  const int tid = threadIdx.x;
  const int w = tid >> 6, lane = tid & 63;
  const int lr = lane & 15, lk = lane >> 4;
  const int qbA = qp, qbB = 31 - qp;
  const int qrowA = qbA * 64 + w * 16;   // within batch
  const int qrowB = qbB * 64 + w * 16;

  __shared__ bf16 Ks[64 * 64];
  __shared__ bf16 Vs[64 * 64];          // V^T tile: [d][key]
  __shared__ bf16 Ps[4][16 * 64];

  const bf16* qpa = QKV + (size_t)(batch * 2048 + qrowA + lr) * 3072 + head * 64 + lk * 8;
  const bf16* qpb = QKV + (size_t)(batch * 2048 + qrowB + lr) * 3072 + head * 64 + lk * 8;
  const bf16x8 aqA0 = *(const bf16x8*)qpa, aqA1 = *(const bf16x8*)(qpa + 32);
  const bf16x8 aqB0 = *(const bf16x8*)qpb, aqB1 = *(const bf16x8*)(qpb + 32);

  const f32x4 z4 = {0.f, 0.f, 0.f, 0.f};
  float mA[4], lA[4], mB[4], lB[4];
  f32x4 coA[4], coB[4];
#pragma unroll
  for (int r = 0; r < 4; ++r) { mA[r] = mB[r] = -1e30f; lA[r] = lB[r] = 0.f; }
#pragma unroll
  for (int nd = 0; nd < 4; ++nd) { coA[nd] = z4; coB[nd] = z4; }

  const bf16* kbase = QKV + (size_t)(batch * 2048) * 3072 + 1024 + head * 64;
  const bf16* vbase = VT + (size_t)(head * 64) * 4096 + batch * 2048;
  const int srow = tid >> 3;                        // 0..31
  const int scol = (tid & 7) * 8;                   // global element col
  const int swoff = ((tid & 7) ^ (srow & 7)) * 8;   // swizzled LDS element col
  const int eQ = (lk ^ (lr & 7)) << 3;              // swizzled read offset (rows ≡ lr mod 8)

  // one K/V tile step for one q-tile
  auto attn_step = [&](int qrow_w, bool diag, int kb64, float* m0, float* l0,
                       f32x4* co, bf16x8 aq0, bf16x8 aq1) {
    f32x4 sv[4];
#pragma unroll
    for (int ni = 0; ni < 4; ++ni) {
      const bf16x8 bk0 = *(const bf16x8*)&Ks[(ni * 16 + lr) * 64 + eQ];
      const bf16x8 bk1 = *(const bf16x8*)&Ks[(ni * 16 + lr) * 64 + (eQ ^ 32)];
      f32x4 z = z4;
      z = MFMA16(aq0, bk0, z);
      z = MFMA16(aq1, bk1, z);
      sv[ni] = z;
    }
#pragma unroll
    for (int ni = 0; ni < 4; ++ni)
#pragma unroll
      for (int r = 0; r < 4; ++r) {
        float v = sv[ni][r] * 0.125f;
        if (diag && (kb64 + ni * 16 + lr > qrow_w + lk * 4 + r)) v = -1e30f;
        sv[ni][r] = v;
      }
    float fac[4];
#pragma unroll
    for (int r = 0; r < 4; ++r) {
      float mx = fmaxf(fmaxf(sv[0][r], sv[1][r]), fmaxf(sv[2][r], sv[3][r]));
      mx = fmaxf(mx, __shfl_xor(mx, 1));
      mx = fmaxf(mx, __shfl_xor(mx, 2));
      mx = fmaxf(mx, __shfl_xor(mx, 4));
      mx = fmaxf(mx, __shfl_xor(mx, 8));
      const float mn = fmaxf(m0[r], mx);
      fac[r] = __expf(m0[r] - mn);
      m0[r] = mn;
    }
#pragma unroll
    for (int ni = 0; ni < 4; ++ni)
#pragma unroll
      for (int r = 0; r < 4; ++r) sv[ni][r] = __expf(sv[ni][r] - m0[r]);
#pragma unroll
    for (int r = 0; r < 4; ++r) {
      float ps = sv[0][r] + sv[1][r] + sv[2][r] + sv[3][r];
      ps += __shfl_xor(ps, 1);
      ps += __shfl_xor(ps, 2);
      ps += __shfl_xor(ps, 4);
      ps += __shfl_xor(ps, 8);
      l0[r] = l0[r] * fac[r] + ps;
    }
    // P -> LDS (per-wave slice, C-layout -> [qrow][key], swizzled)
#pragma unroll
    for (int ni = 0; ni < 4; ++ni)
#pragma unroll
      for (int r = 0; r < 4; ++r) {
        const int prow = lk * 4 + r;
        const int pcol = (((ni * 2 + (lr >> 3)) ^ (prow & 7)) << 3) + (lr & 7);
        Ps[w][prow * 64 + pcol] = __float2bfloat16(sv[ni][r]);
      }
#pragma unroll
    for (int nd = 0; nd < 4; ++nd)
#pragma unroll
      for (int r = 0; r < 4; ++r) co[nd][r] *= fac[r];
#pragma unroll
    for (int kk = 0; kk < 2; ++kk) {
      const int ep = kk ? (eQ ^ 32) : eQ;    // chunk (kk*4+lk) ^ (lr&7)
      const bf16x8 ap = *(const bf16x8*)&Ps[w][lr * 64 + ep];
#pragma unroll
      for (int nd = 0; nd < 4; ++nd) {
        const bf16x8 bv = *(const bf16x8*)&Vs[(nd * 16 + lr) * 64 + ep];
        co[nd] = MFMA16(ap, bv, co[nd]);
      }
    }
  };

  for (int kb = 0; kb <= qbB; ++kb) {
    const int kb64 = kb * 64;
    // stage K [key][d] and V^T [d][key] tiles (coalesced 16B, swizzled LDS col)
    *(int4*)&Ks[srow * 64 + swoff]        = *(const int4*)&kbase[(size_t)(kb64 + srow) * 3072 + scol];
    *(int4*)&Ks[(srow + 32) * 64 + swoff] = *(const int4*)&kbase[(size_t)(kb64 + srow + 32) * 3072 + scol];
    *(int4*)&Vs[srow * 64 + swoff]        = *(const int4*)&vbase[(size_t)srow * 4096 + kb64 + scol];
    *(int4*)&Vs[(srow + 32) * 64 + swoff] = *(const int4*)&vbase[(size_t)(srow + 32) * 4096 + kb64 + scol];
    __syncthreads();

    attn_step(qrowB, kb == qbB, kb64, mB, lB, coB, aqB0, aqB1);
    if (kb <= qbA)
      attn_step(qrowA, kb == qbA, kb64, mA, lA, coA, aqA0, aqA1);
    __syncthreads();
  }

  // write ctx[token][head*64+d] (bf16) for both q-tiles
#pragma unroll
  for (int nd = 0; nd < 4; ++nd)
#pragma unroll
    for (int r = 0; r < 4; ++r) {
      const size_t rowA = (size_t)(batch * 2048 + qrowA + lk * 4 + r);
      ctx[rowA * 1024 + head * 64 + nd * 16 + lr] = __float2bfloat16(coA[nd][r] / lA[r]);
      const size_t rowB = (size_t)(batch * 2048 + qrowB + lk * 4 + r);
      ctx[rowB * 1024 + head * 64 + nd * 16 + lr] = __float2bfloat16(coB[nd][r] / lB[r]);
    }
}

// ---------------- launch ----------------
extern "C" void kernel_launch(void* const* d_in, const int* in_sizes, int n_in,
                              void* d_out, int out_size, void* d_ws, size_t ws_size,
                              hipStream_t stream) {
  const float* x    = (const float*)d_in[0];
  const float* Wq   = (const float*)d_in[1];
  const float* Wk   = (const float*)d_in[2];
  const float* Wv   = (const float*)d_in[3];
  const float* Wo   = (const float*)d_in[4];
  const float* bo   = (const float*)d_in[5];
  const float* W1   = (const float*)d_in[6];
  const float* b1   = (const float*)d_in[7];
  const float* W2   = (const float*)d_in[8];
  const float* b2   = (const float*)d_in[9];
  const float* ln1s = (const float*)d_in[10];
  const float* ln1b = (const float*)d_in[11];
  const float* ln2s = (const float*)d_in[12];
  const float* ln2b = (const float*)d_in[13];
  float* out = (float*)d_out;

  char* ws = (char*)d_ws;
  const size_t MB = 1ull << 20;
  bf16* WqkvT = (bf16*)(ws + 0);        // [3072][1024]  (Wq|Wk|Wv transposed)
  bf16* WoT   = (bf16*)(ws + 6 * MB);   // [1024][1024]
  bf16* W1T   = (bf16*)(ws + 8 * MB);   // [4096][1024]
  bf16* W2T   = (bf16*)(ws + 16 * MB);  // [1024][4096]
  bf16* h1    = (bf16*)(ws + 24 * MB);  // [4096][1024]  (reused as h2)
  bf16* QKV   = (bf16*)(ws + 32 * MB);  // [4096][3072]
  bf16* VT    = (bf16*)(ws + 56 * MB);  // [1024][4096]
  bf16* f1    = (bf16*)(ws + 32 * MB);  // [4096][4096]  overlays QKV+VT (dead by then)
  bf16* ctx   = (bf16*)(ws + 64 * MB);  // [4096][1024]
  // x1 (fp32) lives in d_out. Total ws: 72 MB.

  const dim3 T(256);

  // weight transposes + fp32->bf16
  transpose_bf16_k<float><<<dim3(32, 32), T, 0, stream>>>(Wq, WqkvT, 1024, 1024);
  transpose_bf16_k<float><<<dim3(32, 32), T, 0, stream>>>(Wk, WqkvT + 1024 * 1024, 1024, 1024);
  transpose_bf16_k<float><<<dim3(32, 32), T, 0, stream>>>(Wv, WqkvT + 2048 * 1024, 1024, 1024);
  transpose_bf16_k<float><<<dim3(32, 32), T, 0, stream>>>(Wo, WoT, 1024, 1024);
  transpose_bf16_k<float><<<dim3(128, 32), T, 0, stream>>>(W1, W1T, 4096, 1024);
  transpose_bf16_k<float><<<dim3(32, 128), T, 0, stream>>>(W2, W2T, 1024, 4096);

  // LN1 -> h1 (bf16)
  ln_fwd_k<<<4096, T, 0, stream>>>(x, ln1s, ln1b, h1);

  // QKV = h1 @ [Wq|Wk|Wv]   -> [4096][3072] bf16
  gemm_bt_k<EPI_BF16, 128><<<dim3(24, 32), T, 0, stream>>>(
      h1, WqkvT, QKV, nullptr, nullptr, 4096, 3072, 1024);

  // V^T  [1024][4096] for PV fragment reads
  transpose_bf16_k<bf16><<<dim3(32, 128), T, 0, stream>>>(QKV + 2048, VT, 3072, 4096);

  // attention -> ctx bf16  (16 q-pairs x 16 heads x 2 batches)
  attn_fwd_k<<<dim3(16, 16, 2), T, 0, stream>>>(QKV, VT, ctx);

  // x1 = ctx @ Wo + bo + x   -> d_out (fp32)   [N=1024: BN=64, 512 blocks]
  gemm_bt_k<EPI_BIAS_RES_F32, 64><<<dim3(16, 32), T, 0, stream>>>(
      ctx, WoT, out, bo, x, 4096, 1024, 1024);

  // LN2(x1) -> h2 (reuse h1)
  ln_fwd_k<<<4096, T, 0, stream>>>(out, ln2s, ln2b, h1);

  // f1 = gelu(h2 @ W1 + b1)  -> [4096][4096] bf16
  gemm_bt_k<EPI_GELU_BF16, 128><<<dim3(32, 32), T, 0, stream>>>(
      h1, W1T, f1, b1, nullptr, 4096, 4096, 1024);

  // out = f1 @ W2 + b2 + x1  (read-modify-write on d_out) [N=1024: BN=64]
  gemm_bt_k<EPI_BIAS_RES_F32, 64><<<dim3(16, 32), T, 0, stream>>>(
      f1, W2T, out, b2, out, 4096, 1024, 4096);
}